// Round 18
// baseline (115.864 us; speedup 1.0000x reference)
//
#include <hip/hip_runtime.h>
#include <hip/hip_bf16.h>

typedef unsigned short u16;
typedef unsigned int u32;
typedef short short8 __attribute__((ext_vector_type(8)));
typedef u16 u16x8 __attribute__((ext_vector_type(8)));
typedef u16 u16x4 __attribute__((ext_vector_type(4)));
typedef u32 u32x4 __attribute__((ext_vector_type(4)));
typedef float f32x4 __attribute__((ext_vector_type(4)));
typedef float f32x16 __attribute__((ext_vector_type(16)));

#define MFMA(a, b, c) __builtin_amdgcn_mfma_f32_16x16x32_bf16((a), (b), (c), 0, 0, 0)
#define MFMA32(a, b, c) __builtin_amdgcn_mfma_f32_32x32x16_bf16((a), (b), (c), 0, 0, 0)

// log2(e)*0.125 folded into Q at projection time; softmax runs in exp2 domain.
#define QSCALE 0.18033688011112042f

// ---------- helpers ----------
__device__ __forceinline__ u16 f2bf(float f) {
  unsigned u = __float_as_uint(f);
  unsigned r = (u + 0x7fffu + ((u >> 16) & 1u)) >> 16;  // RNE
  return (u16)r;
}
__device__ __forceinline__ float bf2f(u16 h) {
  return __uint_as_float(((unsigned)h) << 16);
}
__device__ __forceinline__ float exp2hw(float x) {
  float r;
  asm("v_exp_f32 %0, %1" : "=v"(r) : "v"(x));
  return r;
}
__device__ __forceinline__ u32 cvtpk(float lo, float hi) {
  u32 d;
  asm("v_cvt_pk_bf16_f32 %0, %1, %2" : "=v"(d) : "v"(lo), "v"(hi));
  return d;
}
__device__ __forceinline__ float max3f(float a, float b, float c) {
  float d;
  asm("v_max3_f32 %0, %1, %2, %3" : "=v"(d) : "v"(a), "v"(b), "v"(c));
  return d;
}
// v_permlane32_swap: a[32:63] <-> b[0:31]; both registers updated.
__device__ __forceinline__ void plswap(u32& a, u32& b) {
  asm volatile("v_permlane32_swap_b32 %0, %1" : "+v"(a), "+v"(b));
}
__device__ __forceinline__ void async16(const void* g, void* l) {
  __builtin_amdgcn_global_load_lds(
      (const __attribute__((address_space(1))) void*)g,
      (__attribute__((address_space(3))) void*)l, 16, 0, 0);
}
__device__ __forceinline__ f32x16 zero16() {
  f32x16 z;
#pragma unroll
  for (int i = 0; i < 16; i++) z[i] = 0.f;
  return z;
}
// counted waits (T4): keep prefetch loads in flight across barriers
#define WAITV(N) asm volatile("s_waitcnt vmcnt(" #N ")" ::: "memory")
#define WAITL0() asm volatile("s_waitcnt lgkmcnt(0)" ::: "memory")
#define BAR() __builtin_amdgcn_s_barrier()
#define PRIO1 __builtin_amdgcn_s_setprio(1)
#define PRIO0 __builtin_amdgcn_s_setprio(0)

// ---------- 1. f32 -> bf16 convert (x, wq, wk, wv, wo) + RoPE cos/sin table
__global__ __launch_bounds__(256) void convert_kernel(
    const float* __restrict__ x, const float* __restrict__ wq,
    const float* __restrict__ wk, const float* __restrict__ wv,
    const float* __restrict__ wo, u16* __restrict__ ws,
    const int* __restrict__ tp, float* __restrict__ tab) {
  int blk = blockIdx.x;
  if (blk >= 4096) {
    // RoPE table: tab[bs*64 + p*2 + {0,1}] = cos/sin(tp[bs] * freq_p)
    int t = (blk - 4096) * 256 + threadIdx.x;  // 131072
    int bs = t >> 5, p = t & 31;
    float freq = exp2hw(-(float)p * 0.4152410118609203f);
    float ang = (float)tp[bs] * freq;
    float sn, cs;
    sincosf(ang, &sn, &cs);
    tab[bs * 64 + p * 2] = cs;
    tab[bs * 64 + p * 2 + 1] = sn;
    return;
  }
  const float* src; u16* dst;
  if (blk < 2048)      { src = x;  dst = ws; }
  else if (blk < 2560) { src = wq; dst = ws + 4194304;               blk -= 2048; }
  else if (blk < 3072) { src = wk; dst = ws + 4194304 + 1048576;     blk -= 2560; }
  else if (blk < 3584) { src = wv; dst = ws + 4194304 + 2 * 1048576; blk -= 3072; }
  else                 { src = wo; dst = ws + 4194304 + 3 * 1048576; blk -= 3584; }
  int idx = (blk * 256 + threadIdx.x) * 8;
  float4 v0 = *(const float4*)(src + idx);
  float4 v1 = *(const float4*)(src + idx + 4);
  u16x8 o;
  o[0] = f2bf(v0.x); o[1] = f2bf(v0.y); o[2] = f2bf(v0.z); o[3] = f2bf(v0.w);
  o[4] = f2bf(v1.x); o[5] = f2bf(v1.y); o[6] = f2bf(v1.z); o[7] = f2bf(v1.w);
  *(u16x8*)(dst + idx) = o;
}

// ---------- 2. fused QKV projection: ONE GEMM, M=4096 N=3072.
// Tile 128x192 -> grid 32x16 = 512 blocks, LDS 80 KB -> 2 blocks/CU: two
// independent barrier domains per CU hide the stage-wait (m114 mechanism;
// the round-9/15 lever applied to the GEMM). 8 waves (2M x 4N), per-wave
// 64x48, single-phase K-loop with counted vmcnt (gemm_ao structure).
__global__ __launch_bounds__(512) void gemm_qkv256(
    const u16* __restrict__ xb, const u16* __restrict__ Wg,
    const float* __restrict__ tab, u16* __restrict__ qb, u16* __restrict__ kb,
    u16* __restrict__ vt) {
  __shared__ u16 As[2][8192];   // [tile-buf][128 x 64]
  __shared__ u16 Bs[2][12288];  // [tile-buf][192 x 64]
  const int tid = threadIdx.x, lane = tid & 63, wid = tid >> 6;
  const int wm = wid >> 2, wn = wid & 3;
  const int g = lane >> 4, r = lane & 15;
  const int lid = ((blockIdx.x & 7) << 6) + (blockIdx.x >> 3);  // bijective
  const int rowBase = (lid >> 4) << 7;       // M tile (128), 32 row-tiles
  const int colBase = (lid & 15) * 192;      // N tile (192) in [0, 3072)

  // staging: A = 1024 chunks (2/thread), B = 1536 chunks (3/thread)
#define STG_A(BUF, T)                                                         \
  do {                                                                        \
    _Pragma("unroll") for (int i_ = 0; i_ < 2; ++i_) {                        \
      int c = i_ * 512 + tid;                                                 \
      int row = c >> 3, kc = ((c & 7) ^ (row & 7)) * 8;                       \
      async16(xb + (size_t)(rowBase + row) * 1024 + ((T) << 6) + kc,          \
              (char*)As[BUF] + c * 16);                                       \
    }                                                                         \
  } while (0)
#define STG_B(BUF, T)                                                         \
  do {                                                                        \
    _Pragma("unroll") for (int i_ = 0; i_ < 3; ++i_) {                        \
      int c = i_ * 512 + tid;                                                 \
      int row = c >> 3, kc = ((c & 7) ^ (row & 7)) * 8;                       \
      async16(Wg + (size_t)(colBase + row) * 1024 + ((T) << 6) + kc,          \
              (char*)Bs[BUF] + c * 16);                                       \
    }                                                                         \
  } while (0)

  f32x4 acc[4][3];
#pragma unroll
  for (int m = 0; m < 4; m++)
#pragma unroll
    for (int n = 0; n < 3; n++) acc[m][n] = (f32x4){0.f, 0.f, 0.f, 0.f};

  STG_A(0, 0); STG_B(0, 0);
  for (int t = 0; t < 16; ++t) {
    const int cur = t & 1;
    if (t + 1 < 16) {
      STG_A(cur ^ 1, t + 1);
      STG_B(cur ^ 1, t + 1);  // 10 outstanding; wait oldest 5 (= tile t)
      WAITV(5);
    } else {
      WAITV(0);
    }
    BAR();
    const u16* Ab = As[cur];
    const u16* Bb = Bs[cur];
    short8 af[4][2], bfr[3][2];
#pragma unroll
    for (int m = 0; m < 4; m++) {
      int ra = wm * 64 + m * 16 + r;
      const u16* p = Ab + ra * 64;
      int sw = (ra & 7) << 3;
      af[m][0] = *(const short8*)(p + ((g << 3) ^ sw));
      af[m][1] = *(const short8*)(p + (((4 + g) << 3) ^ sw));
    }
#pragma unroll
    for (int n = 0; n < 3; n++) {
      int cb = wn * 48 + n * 16 + r;
      const u16* p = Bb + cb * 64;
      int sw = (cb & 7) << 3;
      bfr[n][0] = *(const short8*)(p + ((g << 3) ^ sw));
      bfr[n][1] = *(const short8*)(p + (((4 + g) << 3) ^ sw));
    }
    PRIO1;
#pragma unroll
    for (int m = 0; m < 4; m++)
#pragma unroll
      for (int n = 0; n < 3; n++) {
        acc[m][n] = MFMA(af[m][0], bfr[n][0], acc[m][n]);
        acc[m][n] = MFMA(af[m][1], bfr[n][1], acc[m][n]);
      }
    PRIO0;
    WAITL0();
    BAR();
  }
#undef STG_A
#undef STG_B

  // epilogue: fragment column range never straddles a 1024-col weight
  // boundary (bases are multiples of 16) -> z = col>>10 is wave-uniform.
  const int colF = colBase + wn * 48;
#pragma unroll
  for (int n = 0; n < 3; n++) {
    const int col3 = colF + n * 16 + r;
    const int z = col3 >> 10;
    const int col = col3 & 1023;
    if (z < 2) {
      // RoPE fused: pair (2p,2p+1) = adjacent cols = adjacent lanes (r, r^1)
      u16* dst = z ? kb : qb;
      const float qs = z ? 1.0f : QSCALE;
      const int p2 = (col >> 1) & 31;
      const bool odd = col & 1;
#pragma unroll
      for (int m = 0; m < 4; m++)
#pragma unroll
        for (int i = 0; i < 4; i++) {
          const int row = rowBase + wm * 64 + m * 16 + g * 4 + i;  // b*2048+s
          float2 cssn = *(const float2*)(tab + row * 64 + p2 * 2);
          float v = acc[m][n][i];
          float part = __shfl_xor(v, 1);
          float res = odd ? (part * cssn.y + v * cssn.x)
                          : (v * cssn.x - part * cssn.y);
          dst[(size_t)row * 1024 + col] = f2bf(res * qs);
        }
    } else {
#pragma unroll
      for (int m = 0; m < 4; m++)
#pragma unroll
        for (int i = 0; i < 4; i++) {
          const int row = rowBase + wm * 64 + m * 16 + g * 4 + i;
          const int bb = row >> 11, s = row & 2047;
          vt[(size_t)((bb * 16 + (col >> 6)) * 64 + (col & 63)) * 2048 + s] =
              f2bf(acc[m][n][i]);
        }
    }
  }
}

// ---------- 4a. flash attention pass 1: 2-way KV-split ----------
// Block = (a, k, c, bh): rows [k*64,k*64+64) of q-tiles {a, 15-a}, KV tiles
// j = c (mod 2). 1024 blocks x 4 waves, 32 KB dbuf LDS, VGPR cap 128.
__global__ __launch_bounds__(256, 4) void attn_kernel(
    const u16* __restrict__ qg, const u16* __restrict__ kg,
    const u16* __restrict__ vt, u16* __restrict__ p0, u16* __restrict__ p1,
    float* __restrict__ mbuf, float* __restrict__ lbuf) {
  __shared__ u16 Ks[2][64 * 64];
  __shared__ u16 Vs[2][64 * 64];
  const int tid = threadIdx.x, wid = tid >> 6, lane = tid & 63;
  const int q5 = lane & 31, hi = lane >> 5;
  const int akc = blockIdx.x >> 5, bh = blockIdx.x & 31;
  const int a = akc >> 2, k = (akc >> 1) & 1, c = akc & 1;
  const int b = bh >> 4, h = bh & 15;
  const int base = (wid < 2) ? a : (15 - a);
  const int rb = base * 128 + k * 64 + (wid & 1) * 32;  // wave q base
  const int cmax = rb >> 5;          // last active 32-kv chunk index
  const int jend = 30 - 2 * a + k;   // block-uniform last KV-tile
  const int qrow = (b << 11) + rb + q5;

  // Q B-fragments: bq[kk] = row qrow, d = kk*16 + hi*8 + {0..7}
  short8 bq[4];
  {
    const u16* qp = qg + (size_t)qrow * 1024 + (h << 6) + hi * 8;
    bq[0] = *(const short8*)(qp);
    bq[1] = *(const short8*)(qp + 16);
    bq[2] = *(const short8*)(qp + 32);
    bq[3] = *(const short8*)(qp + 48);
  }
  f32x16 accO0 = zero16(), accO1 = zero16();  // d 0-31 / 32-63
  float m_r = -1e30f, l_r = 0.f;

#define STAGE(JT, BUF)                                                        \
  do {                                                                        \
    _Pragma("unroll") for (int i_ = 0; i_ < 2; i_++) {                        \
      int cc_ = i_ * 256 + tid;                                               \
      int row = cc_ >> 3, cc = (cc_ & 7) ^ (row & 7);                         \
      async16(kg + (size_t)((b << 11) + ((JT) << 6) + row) * 1024 +           \
                  (h << 6) + cc * 8,                                          \
              (char*)Ks[BUF] + cc_ * 16);                                     \
      async16(vt + (size_t)((bh << 6) + row) * 2048 + ((JT) << 6) + cc * 8,   \
              (char*)Vs[BUF] + cc_ * 16);                                     \
    }                                                                         \
  } while (0)

  if (c <= jend) STAGE(c, 0);

  for (int jj = c; jj <= jend; jj += 2) {
    const int cur = ((jj - c) >> 1) & 1;
    if (jj + 2 <= jend) {
      STAGE(jj + 2, cur ^ 1);  // 8 outstanding; drain oldest 4 (= tile jj)
      WAITV(4);
    } else {
      WAITV(0);
    }
    BAR();
    if (2 * jj <= cmax) {  // wave-uniform activity
      const u16* Kb = Ks[cur];
      const u16* Vb = Vs[cur];
      const bool has1 = (2 * jj + 1 <= cmax);
      const int rsw = (q5 & 7) << 3;
      // ---- QK^T: S^T chunks (kv 0-31, 32-63), col = q
      f32x16 s0 = zero16(), s1 = zero16();
      PRIO1;
#pragma unroll
      for (int kk = 0; kk < 4; kk++) {
        short8 kf =
            *(const short8*)(Kb + q5 * 64 + ((((kk << 1) + hi) << 3) ^ rsw));
        s0 = MFMA32(kf, bq[kk], s0);
      }
      PRIO0;
      if (has1) {
        PRIO1;
#pragma unroll
        for (int kk = 0; kk < 4; kk++) {
          short8 kf = *(const short8*)(Kb + (32 + q5) * 64 +
                                       ((((kk << 1) + hi) << 3) ^ rsw));
          s1 = MFMA32(kf, bq[kk], s1);
        }
        PRIO0;
      }
      // ---- causal mask on the boundary chunk (rowk > q5)
      if (2 * jj == cmax) {
#pragma unroll
        for (int rg = 0; rg < 16; rg++) {
          int rowk = (rg & 3) + 8 * (rg >> 2) + 4 * hi;
          if (rowk > q5) s0[rg] = -1e30f;
        }
      } else if (2 * jj + 1 == cmax) {
#pragma unroll
        for (int rg = 0; rg < 16; rg++) {
          int rowk = (rg & 3) + 8 * (rg >> 2) + 4 * hi;
          if (rowk > q5) s1[rg] = -1e30f;
        }
      }
      // ---- online softmax (lane owns one q-row; partner = lane^32)
      // max-reduce via v_max3_f32 (T17)
      float pmax = max3f(s0[0], s0[1], s0[2]);
#pragma unroll
      for (int rg = 3; rg < 15; rg += 2) pmax = max3f(pmax, s0[rg], s0[rg + 1]);
      pmax = fmaxf(pmax, s0[15]);
      if (has1) {
#pragma unroll
        for (int rg = 0; rg < 16; rg += 2) pmax = max3f(pmax, s1[rg], s1[rg + 1]);
      }
      pmax = fmaxf(pmax, __shfl_xor(pmax, 32));
      if (!__all(pmax <= m_r + 8.0f)) {  // T13 defer-max
        float mn = fmaxf(m_r, pmax);
        float sc = exp2hw(m_r - mn);
        l_r *= sc;
#pragma unroll
        for (int rg = 0; rg < 16; rg++) {
          accO0[rg] *= sc;
          accO1[rg] *= sc;
        }
        m_r = mn;
      }
      // ---- exp + pack + permlane-swap into PV B-fragments
      float rs = 0.f;
      u32 pw00[4], pw01[4], pw10[4], pw11[4];
#define PACK(SREG, OUT, S16)                                                  \
  do {                                                                        \
    float pp0 = exp2hw(SREG[(S16)*8 + 0] - m_r);                              \
    float pp1 = exp2hw(SREG[(S16)*8 + 1] - m_r);                              \
    float pp2 = exp2hw(SREG[(S16)*8 + 2] - m_r);                              \
    float pp3 = exp2hw(SREG[(S16)*8 + 3] - m_r);                              \
    float pp4 = exp2hw(SREG[(S16)*8 + 4] - m_r);                              \
    float pp5 = exp2hw(SREG[(S16)*8 + 5] - m_r);                              \
    float pp6 = exp2hw(SREG[(S16)*8 + 6] - m_r);                              \
    float pp7 = exp2hw(SREG[(S16)*8 + 7] - m_r);                              \
    rs += ((pp0 + pp1) + (pp2 + pp3)) + ((pp4 + pp5) + (pp6 + pp7));          \
    u32 X = cvtpk(pp0, pp1), Y = cvtpk(pp2, pp3);                             \
    u32 U = cvtpk(pp4, pp5), W = cvtpk(pp6, pp7);                             \
    plswap(X, U);                                                             \
    plswap(Y, W);                                                             \
    OUT[0] = X; OUT[1] = Y; OUT[2] = U; OUT[3] = W;                           \
  } while (0)
      PACK(s0, pw00, 0);
      PACK(s0, pw01, 1);
      if (has1) {
        PACK(s1, pw10, 0);
        PACK(s1, pw11, 1);
      }
#undef PACK
      rs += __shfl_xor(rs, 32);
      l_r += rs;
      // ---- PV: O^T += V^T * P  (A = V^T from LDS, B = packed P frags)
#define PVSTEP(PW, CH)                                                        \
  do {                                                                        \
    u32x4 pv_ = {PW[0], PW[1], PW[2], PW[3]};                                 \
    short8 pb_ = __builtin_bit_cast(short8, pv_);                             \
    short8 v0_ =                                                              \
        *(const short8*)(Vb + q5 * 64 + ((((CH) + hi) << 3) ^ rsw));          \
    short8 v1_ = *(const short8*)(Vb + (32 + q5) * 64 +                       \
                                  ((((CH) + hi) << 3) ^ rsw));                \
    accO0 = MFMA32(v0_, pb_, accO0);                                          \
    accO1 = MFMA32(v1_, pb_, accO1);                                          \
  } while (0)
      PRIO1;
      PVSTEP(pw00, 0);
      PVSTEP(pw01, 2);
      if (has1) {
        PVSTEP(pw10, 4);
        PVSTEP(pw11, 6);
      }
      PRIO0;
#undef PVSTEP
    }
    WAITL0();  // own LDS reads done -> WAR-safe
    BAR();
  }
#undef STAGE

  // epilogue: write UNNORMALIZED partial; d = qd*8 + hi*4 + {0..3} (+32)
  u16* pout = c ? p1 : p0;
#pragma unroll
  for (int qd = 0; qd < 4; qd++) {
    u16x4 o0, o1;
#pragma unroll
    for (int e = 0; e < 4; e++) {
      o0[e] = f2bf(accO0[qd * 4 + e]);
      o1[e] = f2bf(accO1[qd * 4 + e]);
    }
    u16* op = pout + (size_t)qrow * 1024 + (h << 6) + qd * 8 + hi * 4;
    *(u16x4*)(op) = o0;
    *(u16x4*)(op + 32) = o1;
  }
  if (hi == 0) {
    int mli = c * 65536 + (bh << 11) + rb + q5;
    mbuf[mli] = m_r;
    lbuf[mli] = l_r;
  }
}

// ---------- 4b. merge the two KV-split partials: ab = (O0 w0 + O1 w1)/l ----
__global__ __launch_bounds__(256) void attn_merge(const u16* __restrict__ p1,
                                                  const float* __restrict__ mbuf,
                                                  const float* __restrict__ lbuf,
                                                  u16* __restrict__ ab) {
  int t = blockIdx.x * 256 + threadIdx.x;  // 524288
  int dg = t & 7, row = t >> 3;            // row in [0, 65536)
  int bh = row >> 11, s = row & 2047;
  int b = bh >> 4, h = bh & 15;
  size_t addr = (size_t)((b << 11) + s) * 1024 + (h << 6) + dg * 8;
  float m0 = mbuf[row], m1 = mbuf[65536 + row];
  float l0 = lbuf[row], l1 = lbuf[65536 + row];
  float m = fmaxf(m0, m1);
  float w0 = exp2hw(m0 - m), w1 = exp2hw(m1 - m);
  float inv = 1.0f / (l0 * w0 + l1 * w1);
  u16x8 o0 = *(const u16x8*)(ab + addr);
  u16x8 o1 = *(const u16x8*)(p1 + addr);
  u16x8 o;
#pragma unroll
  for (int i = 0; i < 8; i++)
    o[i] = f2bf((bf2f(o0[i]) * w0 + bf2f(o1[i]) * w1) * inv);
  *(u16x8*)(ab + addr) = o;
}

// ---------- 5. output projection: out = attn * wo^T (f32 out) ----------
// 128x128 tile, 512 threads / 8 waves (2M x 4N, per-wave 64x32). Counted
// vmcnt, XCD-swizzled 1D grid (256 blocks).
__global__ __launch_bounds__(512) void gemm_ao(const u16* __restrict__ ab,
                                               const u16* __restrict__ wob,
                                               float* __restrict__ out) {
  __shared__ u16 As[2][8192], Bs[2][8192];  // [tile-buf][128 x 64]
  const int tid = threadIdx.x, lane = tid & 63, wid = tid >> 6;
  const int wm = wid >> 2, wn = wid & 3;    // 2M x 4N
  const int g = lane >> 4, r = lane & 15;
  const int lid = ((blockIdx.x & 7) << 5) + (blockIdx.x >> 3);  // bijective
  const int rowBase = (lid >> 3) << 7;      // M tile (128), 32 rows of tiles
  const int colBase = (lid & 7) << 7;       // N tile (128), 8 cols

#define AOSTG(KT, BUF)                                                        \
  do {                                                                        \
    _Pragma("unroll") for (int i_ = 0; i_ < 2; ++i_) {                        \
      int c = i_ * 512 + tid;                                                 \
      int row = c >> 3, kc = ((c & 7) ^ (row & 7)) * 8;                       \
      async16(ab + (size_t)(rowBase + row) * 1024 + ((KT) << 6) + kc,         \
              (char*)As[BUF] + c * 16);                                       \
    }                                                                         \
    _Pragma("unroll") for (int i_ = 0; i_ < 2; ++i_) {                        \
      int c = i_ * 512 + tid;                                                 \
      int row = c >> 3, kc = ((c & 7) ^ (row & 7)) * 8;                       \
      async16(wob + (size_t)(colBase + row) * 1024 + ((KT) << 6) + kc,        \
              (char*)Bs[BUF] + c * 16);                                       \
    }                                                                         \
  } while (0)

  f32x4 acc[4][2];
#pragma unroll
  for (int m = 0; m < 4; m++)
#pragma unroll
    for (int n = 0; n < 2; n++) acc[m][n] = (f32x4){0.f, 0.f, 0.f, 0.f};

  AOSTG(0, 0);
  for (int kt = 0; kt < 16; ++kt) {
    const int cur = kt & 1;
    if (kt + 1 < 16) {
      AOSTG(kt + 1, cur ^ 1);  // 8 outstanding; wait oldest 4 (= tile kt)
      WAITV(4);
    } else {
      WAITV(0);
    }
    BAR();
    const u16* Ab = As[cur];
    const u16* Bb = Bs[cur];
    short8 af[4][2], bfr[2][2];
#pragma unroll
    for (int m = 0; m < 4; m++) {
      int ra = wm * 64 + m * 16 + r;
      const u16* p = Ab + ra * 64;
      int sw = (ra & 7) << 3;
      af[m][0] = *(const short8*)(p + ((g << 3) ^ sw));
      af[m][1] = *(const short8*)(p + (((4 + g) << 3) ^ sw));
    }
#pragma unroll
    for (int n = 0; n < 2; n++) {
      int cb = wn * 32 + n * 16 + r;
      const u16* p = Bb + cb * 64;
      int sw = (cb & 7) << 3;
      bfr[n][0] = *(const short8*)(p + ((g << 3) ^ sw));
      bfr[n][1] = *(const short8*)(p + (((4 + g) << 3) ^ sw));
    }
    PRIO1;
#pragma unroll
    for (int m = 0; m < 4; m++)
#pragma unroll
      for (int n = 0; n < 2; n++) {
        acc[m][n] = MFMA(af[m][0], bfr[n][0], acc[m][n]);
        acc[m][n] = MFMA(af[m][1], bfr[n][1], acc[m][n]);
      }
    PRIO0;
    WAITL0();
    BAR();
  }
#undef AOSTG

  const int rowB = rowBase + wm * 64;
  const int colB = colBase + wn * 32;
#pragma unroll
  for (int m = 0; m < 4; m++)
#pragma unroll
    for (int n = 0; n < 2; n++)
#pragma unroll
      for (int i = 0; i < 4; i++)
        out[(size_t)(rowB + m * 16 + g * 4 + i) * 1024 + colB + n * 16 + r] =
            acc[m][n][i];
}

extern "C" void kernel_launch(void* const* d_in, const int* in_sizes, int n_in,
                              void* d_out, int out_size, void* d_ws,
                              size_t ws_size, hipStream_t stream) {
  const float* x = (const float*)d_in[0];
  const int* tp = (const int*)d_in[1];
  const float* wq = (const float*)d_in[2];
  const float* wk = (const float*)d_in[3];
  const float* wv = (const float*)d_in[4];
  const float* wo = (const float*)d_in[5];
  float* out = (float*)d_out;

  u16* ws = (u16*)d_ws;
  u16* xb = ws;                   // 4194304 (partial-1 O after qkv256)
  u16* wqb = xb + 4194304;        // 1048576 — wq|wk|wv CONTIGUOUS (fused B)
  u16* wkb = wqb + 1048576;
  u16* wvb = wkb + 1048576;
  u16* wob = wvb + 1048576;
  u16* qb = wob + 1048576;        // 4194304
  u16* kb = qb + 4194304;
  u16* vtb = kb + 4194304;        // [b][h][d][s]
  u16* ab = vtb + 4194304;        // partial-0 O, then merged attn out
  float* tab = (float*)ab;        // 1 MB, aliases ab (dead before attn writes)
  float* mbuf = (float*)wqb;      // 512 KB (wq weights dead after qkv256)
  float* lbuf = (float*)wkb;      // 512 KB (wk weights dead after qkv256)

  convert_kernel<<<4608, 256, 0, stream>>>(x, wq, wk, wv, wo, ws, tp, tab);
  gemm_qkv256<<<512, 512, 0, stream>>>(xb, wqb, tab, qb, kb, vtb);
  attn_kernel<<<1024, 256, 0, stream>>>(qb, kb, vtb, ab, xb, mbuf, lbuf);
  attn_merge<<<2048, 256, 0, stream>>>(xb, mbuf, lbuf, ab);
  gemm_ao<<<256, 512, 0, stream>>>(ab, wob, out);
}

// Round 19
// 104.684 us; speedup vs baseline: 1.1068x; 1.1068x over previous
//
#include <hip/hip_runtime.h>
#include <hip/hip_bf16.h>

typedef unsigned short u16;
typedef unsigned int u32;
typedef short short8 __attribute__((ext_vector_type(8)));
typedef u16 u16x8 __attribute__((ext_vector_type(8)));
typedef u16 u16x4 __attribute__((ext_vector_type(4)));
typedef u32 u32x4 __attribute__((ext_vector_type(4)));
typedef float f32x4 __attribute__((ext_vector_type(4)));
typedef float f32x16 __attribute__((ext_vector_type(16)));

#define MFMA(a, b, c) __builtin_amdgcn_mfma_f32_16x16x32_bf16((a), (b), (c), 0, 0, 0)
#define MFMA32(a, b, c) __builtin_amdgcn_mfma_f32_32x32x16_bf16((a), (b), (c), 0, 0, 0)

// log2(e)*0.125 folded into Q at projection time; softmax runs in exp2 domain.
#define QSCALE 0.18033688011112042f

// ---------- helpers ----------
__device__ __forceinline__ u16 f2bf(float f) {
  unsigned u = __float_as_uint(f);
  unsigned r = (u + 0x7fffu + ((u >> 16) & 1u)) >> 16;  // RNE
  return (u16)r;
}
__device__ __forceinline__ float bf2f(u16 h) {
  return __uint_as_float(((unsigned)h) << 16);
}
__device__ __forceinline__ float exp2hw(float x) {
  float r;
  asm("v_exp_f32 %0, %1" : "=v"(r) : "v"(x));
  return r;
}
__device__ __forceinline__ u32 cvtpk(float lo, float hi) {
  u32 d;
  asm("v_cvt_pk_bf16_f32 %0, %1, %2" : "=v"(d) : "v"(lo), "v"(hi));
  return d;
}
__device__ __forceinline__ float max3f(float a, float b, float c) {
  float d;
  asm("v_max3_f32 %0, %1, %2, %3" : "=v"(d) : "v"(a), "v"(b), "v"(c));
  return d;
}
// v_permlane32_swap: a[32:63] <-> b[0:31]; both registers updated.
__device__ __forceinline__ void plswap(u32& a, u32& b) {
  asm volatile("v_permlane32_swap_b32 %0, %1" : "+v"(a), "+v"(b));
}
__device__ __forceinline__ void async16(const void* g, void* l) {
  __builtin_amdgcn_global_load_lds(
      (const __attribute__((address_space(1))) void*)g,
      (__attribute__((address_space(3))) void*)l, 16, 0, 0);
}
__device__ __forceinline__ f32x16 zero16() {
  f32x16 z;
#pragma unroll
  for (int i = 0; i < 16; i++) z[i] = 0.f;
  return z;
}
// counted waits (T4): keep prefetch loads in flight across barriers
#define WAITV(N) asm volatile("s_waitcnt vmcnt(" #N ")" ::: "memory")
#define WAITL0() asm volatile("s_waitcnt lgkmcnt(0)" ::: "memory")
#define BAR() __builtin_amdgcn_s_barrier()
#define PRIO1 __builtin_amdgcn_s_setprio(1)
#define PRIO0 __builtin_amdgcn_s_setprio(0)

// ---------- 1. f32 -> bf16 convert (x, wq, wk, wv, wo) + RoPE cos/sin table
__global__ __launch_bounds__(256) void convert_kernel(
    const float* __restrict__ x, const float* __restrict__ wq,
    const float* __restrict__ wk, const float* __restrict__ wv,
    const float* __restrict__ wo, u16* __restrict__ ws,
    const int* __restrict__ tp, float* __restrict__ tab) {
  int blk = blockIdx.x;
  if (blk >= 4096) {
    // RoPE table: tab[bs*64 + p*2 + {0,1}] = cos/sin(tp[bs] * freq_p)
    int t = (blk - 4096) * 256 + threadIdx.x;  // 131072
    int bs = t >> 5, p = t & 31;
    float freq = exp2hw(-(float)p * 0.4152410118609203f);
    float ang = (float)tp[bs] * freq;
    float sn, cs;
    sincosf(ang, &sn, &cs);
    tab[bs * 64 + p * 2] = cs;
    tab[bs * 64 + p * 2 + 1] = sn;
    return;
  }
  const float* src; u16* dst;
  if (blk < 2048)      { src = x;  dst = ws; }
  else if (blk < 2560) { src = wq; dst = ws + 4194304;               blk -= 2048; }
  else if (blk < 3072) { src = wk; dst = ws + 4194304 + 1048576;     blk -= 2560; }
  else if (blk < 3584) { src = wv; dst = ws + 4194304 + 2 * 1048576; blk -= 3072; }
  else                 { src = wo; dst = ws + 4194304 + 3 * 1048576; blk -= 3584; }
  int idx = (blk * 256 + threadIdx.x) * 8;
  float4 v0 = *(const float4*)(src + idx);
  float4 v1 = *(const float4*)(src + idx + 4);
  u16x8 o;
  o[0] = f2bf(v0.x); o[1] = f2bf(v0.y); o[2] = f2bf(v0.z); o[3] = f2bf(v0.w);
  o[4] = f2bf(v1.x); o[5] = f2bf(v1.y); o[6] = f2bf(v1.z); o[7] = f2bf(v1.w);
  *(u16x8*)(dst + idx) = o;
}

// ---------- 2. fused QKV projection: ONE GEMM, M=4096 N=3072, tile 256x192,
// 256 blocks (100% CU fill), XCD-swizzled 1D grid: lid=(bid&7)*32+(bid>>3)
// puts 2 contiguous grid-rows per XCD -> A-panel working set 1 MB (L2-fits).
__global__ __launch_bounds__(512, 2) void gemm_qkv256(
    const u16* __restrict__ xb, const u16* __restrict__ Wg,
    const float* __restrict__ tab, u16* __restrict__ qb, u16* __restrict__ kb,
    u16* __restrict__ vt) {
  __shared__ u16 As[2][16384];  // [tile-buf][256 x 64]
  __shared__ u16 Bs[2][12288];  // [tile-buf][192 x 64]
  const int tid = threadIdx.x, lane = tid & 63, wid = tid >> 6;
  const int wm = wid >> 2, wn = wid & 3;
  const int g = lane >> 4, r = lane & 15;
  const int lid = ((blockIdx.x & 7) << 5) + (blockIdx.x >> 3);  // bijective
  const int rowBase = (lid >> 4) << 8;       // M tile (256)
  const int colBase = (lid & 15) * 192;      // N tile (192) in [0, 3072)

#define STG_A(BUF, T)                                                         \
  do {                                                                        \
    _Pragma("unroll") for (int i_ = 0; i_ < 4; ++i_) {                        \
      int c = i_ * 512 + tid;                                                 \
      int row = c >> 3, kc = ((c & 7) ^ (row & 7)) * 8;                       \
      async16(xb + (size_t)(rowBase + row) * 1024 + (T)*64 + kc,              \
              (char*)As[BUF] + c * 16);                                       \
    }                                                                         \
  } while (0)
#define STG_B(BUF, T)                                                         \
  do {                                                                        \
    _Pragma("unroll") for (int i_ = 0; i_ < 3; ++i_) {                        \
      int c = i_ * 512 + tid;                                                 \
      int row = c >> 3, kc = ((c & 7) ^ (row & 7)) * 8;                       \
      async16(Wg + (size_t)(colBase + row) * 1024 + (T)*64 + kc,              \
              (char*)Bs[BUF] + c * 16);                                       \
    }                                                                         \
  } while (0)

  f32x4 acc[8][3];
#pragma unroll
  for (int m = 0; m < 8; m++)
#pragma unroll
    for (int n = 0; n < 3; n++) acc[m][n] = (f32x4){0.f, 0.f, 0.f, 0.f};
  short8 af[4][2], bfr[3][2];

#define RD_A(CUR, MH)                                                         \
  do {                                                                        \
    _Pragma("unroll") for (int mi = 0; mi < 4; mi++) {                        \
      int ra = wm * 128 + (MH)*64 + mi * 16 + r;                              \
      const u16* p = As[CUR] + ra * 64;                                       \
      int sw = (ra & 7) << 3;                                                 \
      af[mi][0] = *(const short8*)(p + ((g << 3) ^ sw));                      \
      af[mi][1] = *(const short8*)(p + (((4 + g) << 3) ^ sw));                \
    }                                                                         \
  } while (0)
#define RD_B(CUR)                                                             \
  do {                                                                        \
    _Pragma("unroll") for (int ni = 0; ni < 3; ni++) {                        \
      int cb = wn * 48 + ni * 16 + r;                                         \
      const u16* p = Bs[CUR] + cb * 64;                                       \
      int sw = (cb & 7) << 3;                                                 \
      bfr[ni][0] = *(const short8*)(p + ((g << 3) ^ sw));                     \
      bfr[ni][1] = *(const short8*)(p + (((4 + g) << 3) ^ sw));               \
    }                                                                         \
  } while (0)
#define MM24(MH)                                                              \
  do {                                                                        \
    _Pragma("unroll") for (int mi = 0; mi < 4; mi++)                          \
        _Pragma("unroll") for (int ni = 0; ni < 3; ni++) {                    \
      acc[(MH)*4 + mi][ni] = MFMA(af[mi][0], bfr[ni][0], acc[(MH)*4 + mi][ni]); \
      acc[(MH)*4 + mi][ni] = MFMA(af[mi][1], bfr[ni][1], acc[(MH)*4 + mi][ni]); \
    }                                                                         \
  } while (0)

  STG_A(0, 0); STG_B(0, 0);
  STG_A(1, 1);
  WAITV(4);
  BAR();

  for (int t = 0; t < 16; ++t) {
    const int cur = t & 1, nxt = cur ^ 1;
    RD_A(cur, 0);
    RD_B(cur);
    if (t < 15) STG_B(nxt, t + 1);
    BAR(); WAITL0();
    PRIO1; MM24(0); PRIO0; BAR();
    RD_A(cur, 1);
    if (t < 14) {
      STG_A(cur, t + 2);
      WAITV(4);
    } else {
      WAITV(0);
    }
    BAR(); WAITL0();
    PRIO1; MM24(1); PRIO0; BAR();
  }
#undef STG_A
#undef STG_B
#undef RD_A
#undef RD_B
#undef MM24

  const int colF = colBase + wn * 48;
#pragma unroll
  for (int n = 0; n < 3; n++) {
    const int col3 = colF + n * 16 + r;
    const int z = col3 >> 10;
    const int col = col3 & 1023;
    if (z < 2) {
      u16* dst = z ? kb : qb;
      const float qs = z ? 1.0f : QSCALE;
      const int p2 = (col >> 1) & 31;
      const bool odd = col & 1;
#pragma unroll
      for (int m = 0; m < 8; m++)
#pragma unroll
        for (int i = 0; i < 4; i++) {
          const int row = rowBase + wm * 128 + m * 16 + g * 4 + i;  // b*2048+s
          float2 cssn = *(const float2*)(tab + row * 64 + p2 * 2);
          float v = acc[m][n][i];
          float part = __shfl_xor(v, 1);
          float res = odd ? (part * cssn.y + v * cssn.x)
                          : (v * cssn.x - part * cssn.y);
          dst[(size_t)row * 1024 + col] = f2bf(res * qs);
        }
    } else {
#pragma unroll
      for (int m = 0; m < 8; m++)
#pragma unroll
        for (int i = 0; i < 4; i++) {
          const int row = rowBase + wm * 128 + m * 16 + g * 4 + i;
          const int bb = row >> 11, s = row & 2047;
          vt[(size_t)((bb * 16 + (col >> 6)) * 64 + (col & 63)) * 2048 + s] =
              f2bf(acc[m][n][i]);
        }
    }
  }
}

// ---------- 4a. flash attention pass 1: 2-way KV-split ----------
// Block = (a, k, c, bh): rows [k*64,k*64+64) of q-tiles {a, 15-a}, KV tiles
// j = c (mod 2). 1024 blocks x 4 waves, 32 KB dbuf LDS, VGPR cap 128.
__global__ __launch_bounds__(256, 4) void attn_kernel(
    const u16* __restrict__ qg, const u16* __restrict__ kg,
    const u16* __restrict__ vt, u16* __restrict__ p0, u16* __restrict__ p1,
    float* __restrict__ mbuf, float* __restrict__ lbuf) {
  __shared__ u16 Ks[2][64 * 64];
  __shared__ u16 Vs[2][64 * 64];
  const int tid = threadIdx.x, wid = tid >> 6, lane = tid & 63;
  const int q5 = lane & 31, hi = lane >> 5;
  const int akc = blockIdx.x >> 5, bh = blockIdx.x & 31;
  const int a = akc >> 2, k = (akc >> 1) & 1, c = akc & 1;
  const int b = bh >> 4, h = bh & 15;
  const int base = (wid < 2) ? a : (15 - a);
  const int rb = base * 128 + k * 64 + (wid & 1) * 32;  // wave q base
  const int cmax = rb >> 5;          // last active 32-kv chunk index
  const int jend = 30 - 2 * a + k;   // block-uniform last KV-tile
  const int qrow = (b << 11) + rb + q5;

  // Q B-fragments: bq[kk] = row qrow, d = kk*16 + hi*8 + {0..7}
  short8 bq[4];
  {
    const u16* qp = qg + (size_t)qrow * 1024 + (h << 6) + hi * 8;
    bq[0] = *(const short8*)(qp);
    bq[1] = *(const short8*)(qp + 16);
    bq[2] = *(const short8*)(qp + 32);
    bq[3] = *(const short8*)(qp + 48);
  }
  f32x16 accO0 = zero16(), accO1 = zero16();  // d 0-31 / 32-63
  float m_r = -1e30f, l_r = 0.f;

#define STAGE(JT, BUF)                                                        \
  do {                                                                        \
    _Pragma("unroll") for (int i_ = 0; i_ < 2; i_++) {                        \
      int cc_ = i_ * 256 + tid;                                               \
      int row = cc_ >> 3, cc = (cc_ & 7) ^ (row & 7);                         \
      async16(kg + (size_t)((b << 11) + ((JT) << 6) + row) * 1024 +           \
                  (h << 6) + cc * 8,                                          \
              (char*)Ks[BUF] + cc_ * 16);                                     \
      async16(vt + (size_t)((bh << 6) + row) * 2048 + ((JT) << 6) + cc * 8,   \
              (char*)Vs[BUF] + cc_ * 16);                                     \
    }                                                                         \
  } while (0)

  if (c <= jend) STAGE(c, 0);

  for (int jj = c; jj <= jend; jj += 2) {
    const int cur = ((jj - c) >> 1) & 1;
    if (jj + 2 <= jend) {
      STAGE(jj + 2, cur ^ 1);  // 8 outstanding; drain oldest 4 (= tile jj)
      WAITV(4);
    } else {
      WAITV(0);
    }
    BAR();
    if (2 * jj <= cmax) {  // wave-uniform activity
      const u16* Kb = Ks[cur];
      const u16* Vb = Vs[cur];
      const bool has1 = (2 * jj + 1 <= cmax);
      const int rsw = (q5 & 7) << 3;
      // ---- QK^T: S^T chunks (kv 0-31, 32-63), col = q
      f32x16 s0 = zero16(), s1 = zero16();
      PRIO1;
#pragma unroll
      for (int kk = 0; kk < 4; kk++) {
        short8 kf =
            *(const short8*)(Kb + q5 * 64 + ((((kk << 1) + hi) << 3) ^ rsw));
        s0 = MFMA32(kf, bq[kk], s0);
      }
      PRIO0;
      if (has1) {
        PRIO1;
#pragma unroll
        for (int kk = 0; kk < 4; kk++) {
          short8 kf = *(const short8*)(Kb + (32 + q5) * 64 +
                                       ((((kk << 1) + hi) << 3) ^ rsw));
          s1 = MFMA32(kf, bq[kk], s1);
        }
        PRIO0;
      }
      // ---- causal mask on the boundary chunk (rowk > q5)
      if (2 * jj == cmax) {
#pragma unroll
        for (int rg = 0; rg < 16; rg++) {
          int rowk = (rg & 3) + 8 * (rg >> 2) + 4 * hi;
          if (rowk > q5) s0[rg] = -1e30f;
        }
      } else if (2 * jj + 1 == cmax) {
#pragma unroll
        for (int rg = 0; rg < 16; rg++) {
          int rowk = (rg & 3) + 8 * (rg >> 2) + 4 * hi;
          if (rowk > q5) s1[rg] = -1e30f;
        }
      }
      // ---- online softmax (lane owns one q-row; partner = lane^32)
      // max-reduce via v_max3_f32 (T17)
      float pmax = max3f(s0[0], s0[1], s0[2]);
#pragma unroll
      for (int rg = 3; rg < 15; rg += 2) pmax = max3f(pmax, s0[rg], s0[rg + 1]);
      pmax = fmaxf(pmax, s0[15]);
      if (has1) {
#pragma unroll
        for (int rg = 0; rg < 16; rg += 2) pmax = max3f(pmax, s1[rg], s1[rg + 1]);
      }
      pmax = fmaxf(pmax, __shfl_xor(pmax, 32));
      if (!__all(pmax <= m_r + 8.0f)) {  // T13 defer-max
        float mn = fmaxf(m_r, pmax);
        float sc = exp2hw(m_r - mn);
        l_r *= sc;
#pragma unroll
        for (int rg = 0; rg < 16; rg++) {
          accO0[rg] *= sc;
          accO1[rg] *= sc;
        }
        m_r = mn;
      }
      // ---- exp + pack + permlane-swap into PV B-fragments
      float rs = 0.f;
      u32 pw00[4], pw01[4], pw10[4], pw11[4];
#define PACK(SREG, OUT, S16)                                                  \
  do {                                                                        \
    float pp0 = exp2hw(SREG[(S16)*8 + 0] - m_r);                              \
    float pp1 = exp2hw(SREG[(S16)*8 + 1] - m_r);                              \
    float pp2 = exp2hw(SREG[(S16)*8 + 2] - m_r);                              \
    float pp3 = exp2hw(SREG[(S16)*8 + 3] - m_r);                              \
    float pp4 = exp2hw(SREG[(S16)*8 + 4] - m_r);                              \
    float pp5 = exp2hw(SREG[(S16)*8 + 5] - m_r);                              \
    float pp6 = exp2hw(SREG[(S16)*8 + 6] - m_r);                              \
    float pp7 = exp2hw(SREG[(S16)*8 + 7] - m_r);                              \
    rs += ((pp0 + pp1) + (pp2 + pp3)) + ((pp4 + pp5) + (pp6 + pp7));          \
    u32 X = cvtpk(pp0, pp1), Y = cvtpk(pp2, pp3);                             \
    u32 U = cvtpk(pp4, pp5), W = cvtpk(pp6, pp7);                             \
    plswap(X, U);                                                             \
    plswap(Y, W);                                                             \
    OUT[0] = X; OUT[1] = Y; OUT[2] = U; OUT[3] = W;                           \
  } while (0)
      PACK(s0, pw00, 0);
      PACK(s0, pw01, 1);
      if (has1) {
        PACK(s1, pw10, 0);
        PACK(s1, pw11, 1);
      }
#undef PACK
      rs += __shfl_xor(rs, 32);
      l_r += rs;
      // ---- PV: O^T += V^T * P  (A = V^T from LDS, B = packed P frags)
#define PVSTEP(PW, CH)                                                        \
  do {                                                                        \
    u32x4 pv_ = {PW[0], PW[1], PW[2], PW[3]};                                 \
    short8 pb_ = __builtin_bit_cast(short8, pv_);                             \
    short8 v0_ =                                                              \
        *(const short8*)(Vb + q5 * 64 + ((((CH) + hi) << 3) ^ rsw));          \
    short8 v1_ = *(const short8*)(Vb + (32 + q5) * 64 +                       \
                                  ((((CH) + hi) << 3) ^ rsw));                \
    accO0 = MFMA32(v0_, pb_, accO0);                                          \
    accO1 = MFMA32(v1_, pb_, accO1);                                          \
  } while (0)
      PRIO1;
      PVSTEP(pw00, 0);
      PVSTEP(pw01, 2);
      if (has1) {
        PVSTEP(pw10, 4);
        PVSTEP(pw11, 6);
      }
      PRIO0;
#undef PVSTEP
    }
    WAITL0();  // own LDS reads done -> WAR-safe
    BAR();
  }
#undef STAGE

  // epilogue: write UNNORMALIZED partial; d = qd*8 + hi*4 + {0..3} (+32)
  u16* pout = c ? p1 : p0;
#pragma unroll
  for (int qd = 0; qd < 4; qd++) {
    u16x4 o0, o1;
#pragma unroll
    for (int e = 0; e < 4; e++) {
      o0[e] = f2bf(accO0[qd * 4 + e]);
      o1[e] = f2bf(accO1[qd * 4 + e]);
    }
    u16* op = pout + (size_t)qrow * 1024 + (h << 6) + qd * 8 + hi * 4;
    *(u16x4*)(op) = o0;
    *(u16x4*)(op + 32) = o1;
  }
  if (hi == 0) {
    int mli = c * 65536 + (bh << 11) + rb + q5;
    mbuf[mli] = m_r;
    lbuf[mli] = l_r;
  }
}

// ---------- 4b. merge the two KV-split partials: ab = (O0 w0 + O1 w1)/l ----
__global__ __launch_bounds__(256) void attn_merge(const u16* __restrict__ p1,
                                                  const float* __restrict__ mbuf,
                                                  const float* __restrict__ lbuf,
                                                  u16* __restrict__ ab) {
  int t = blockIdx.x * 256 + threadIdx.x;  // 524288
  int dg = t & 7, row = t >> 3;            // row in [0, 65536)
  int bh = row >> 11, s = row & 2047;
  int b = bh >> 4, h = bh & 15;
  size_t addr = (size_t)((b << 11) + s) * 1024 + (h << 6) + dg * 8;
  float m0 = mbuf[row], m1 = mbuf[65536 + row];
  float l0 = lbuf[row], l1 = lbuf[65536 + row];
  float m = fmaxf(m0, m1);
  float w0 = exp2hw(m0 - m), w1 = exp2hw(m1 - m);
  float inv = 1.0f / (l0 * w0 + l1 * w1);
  u16x8 o0 = *(const u16x8*)(ab + addr);
  u16x8 o1 = *(const u16x8*)(p1 + addr);
  u16x8 o;
#pragma unroll
  for (int i = 0; i < 8; i++)
    o[i] = f2bf((bf2f(o0[i]) * w0 + bf2f(o1[i]) * w1) * inv);
  *(u16x8*)(ab + addr) = o;
}

// ---------- 5. output projection: out = attn * wo^T (f32 out) ----------
// 128x128 tile, 512 threads / 8 waves (2M x 4N, per-wave 64x32). Counted
// vmcnt, XCD-swizzled 1D grid (256 blocks).
__global__ __launch_bounds__(512) void gemm_ao(const u16* __restrict__ ab,
                                               const u16* __restrict__ wob,
                                               float* __restrict__ out) {
  __shared__ u16 As[2][8192], Bs[2][8192];  // [tile-buf][128 x 64]
  const int tid = threadIdx.x, lane = tid & 63, wid = tid >> 6;
  const int wm = wid >> 2, wn = wid & 3;    // 2M x 4N
  const int g = lane >> 4, r = lane & 15;
  const int lid = ((blockIdx.x & 7) << 5) + (blockIdx.x >> 3);  // bijective
  const int rowBase = (lid >> 3) << 7;      // M tile (128), 32 rows of tiles
  const int colBase = (lid & 7) << 7;       // N tile (128), 8 cols

#define AOSTG(KT, BUF)                                                        \
  do {                                                                        \
    _Pragma("unroll") for (int i_ = 0; i_ < 2; ++i_) {                        \
      int c = i_ * 512 + tid;                                                 \
      int row = c >> 3, kc = ((c & 7) ^ (row & 7)) * 8;                       \
      async16(ab + (size_t)(rowBase + row) * 1024 + ((KT) << 6) + kc,         \
              (char*)As[BUF] + c * 16);                                       \
    }                                                                         \
    _Pragma("unroll") for (int i_ = 0; i_ < 2; ++i_) {                        \
      int c = i_ * 512 + tid;                                                 \
      int row = c >> 3, kc = ((c & 7) ^ (row & 7)) * 8;                       \
      async16(wob + (size_t)(colBase + row) * 1024 + ((KT) << 6) + kc,        \
              (char*)Bs[BUF] + c * 16);                                       \
    }                                                                         \
  } while (0)

  f32x4 acc[4][2];
#pragma unroll
  for (int m = 0; m < 4; m++)
#pragma unroll
    for (int n = 0; n < 2; n++) acc[m][n] = (f32x4){0.f, 0.f, 0.f, 0.f};

  AOSTG(0, 0);
  for (int kt = 0; kt < 16; ++kt) {
    const int cur = kt & 1;
    if (kt + 1 < 16) {
      AOSTG(kt + 1, cur ^ 1);  // 8 outstanding; wait oldest 4 (= tile kt)
      WAITV(4);
    } else {
      WAITV(0);
    }
    BAR();
    const u16* Ab = As[cur];
    const u16* Bb = Bs[cur];
    short8 af[4][2], bfr[2][2];
#pragma unroll
    for (int m = 0; m < 4; m++) {
      int ra = wm * 64 + m * 16 + r;
      const u16* p = Ab + ra * 64;
      int sw = (ra & 7) << 3;
      af[m][0] = *(const short8*)(p + ((g << 3) ^ sw));
      af[m][1] = *(const short8*)(p + (((4 + g) << 3) ^ sw));
    }
#pragma unroll
    for (int n = 0; n < 2; n++) {
      int cb = wn * 32 + n * 16 + r;
      const u16* p = Bb + cb * 64;
      int sw = (cb & 7) << 3;
      bfr[n][0] = *(const short8*)(p + ((g << 3) ^ sw));
      bfr[n][1] = *(const short8*)(p + (((4 + g) << 3) ^ sw));
    }
    PRIO1;
#pragma unroll
    for (int m = 0; m < 4; m++)
#pragma unroll
      for (int n = 0; n < 2; n++) {
        acc[m][n] = MFMA(af[m][0], bfr[n][0], acc[m][n]);
        acc[m][n] = MFMA(af[m][1], bfr[n][1], acc[m][n]);
      }
    PRIO0;
    WAITL0();
    BAR();
  }
#undef AOSTG

  const int rowB = rowBase + wm * 64;
  const int colB = colBase + wn * 32;
#pragma unroll
  for (int m = 0; m < 4; m++)
#pragma unroll
    for (int n = 0; n < 2; n++)
#pragma unroll
      for (int i = 0; i < 4; i++)
        out[(size_t)(rowB + m * 16 + g * 4 + i) * 1024 + colB + n * 16 + r] =
            acc[m][n][i];
}

extern "C" void kernel_launch(void* const* d_in, const int* in_sizes, int n_in,
                              void* d_out, int out_size, void* d_ws,
                              size_t ws_size, hipStream_t stream) {
  const float* x = (const float*)d_in[0];
  const int* tp = (const int*)d_in[1];
  const float* wq = (const float*)d_in[2];
  const float* wk = (const float*)d_in[3];
  const float* wv = (const float*)d_in[4];
  const float* wo = (const float*)d_in[5];
  float* out = (float*)d_out;

  u16* ws = (u16*)d_ws;
  u16* xb = ws;                   // 4194304 (partial-1 O after qkv256)
  u16* wqb = xb + 4194304;        // 1048576 — wq|wk|wv CONTIGUOUS (fused B)
  u16* wkb = wqb + 1048576;
  u16* wvb = wkb + 1048576;
  u16* wob = wvb + 1048576;
  u16* qb = wob + 1048576;        // 4194304
  u16* kb = qb + 4194304;
  u16* vtb = kb + 4194304;        // [b][h][d][s]
  u16* ab = vtb + 4194304;        // partial-0 O, then merged attn out
  float* tab = (float*)ab;        // 1 MB, aliases ab (dead before attn writes)
  float* mbuf = (float*)wqb;      // 512 KB (wq weights dead after qkv256)
  float* lbuf = (float*)wkb;      // 512 KB (wk weights dead after qkv256)

  convert_kernel<<<4608, 256, 0, stream>>>(x, wq, wk, wv, wo, ws, tp, tab);
  gemm_qkv256<<<256, 512, 0, stream>>>(xb, wqb, tab, qb, kb, vtb);
  attn_kernel<<<1024, 256, 0, stream>>>(qb, kb, vtb, ab, xb, mbuf, lbuf);
  attn_merge<<<2048, 256, 0, stream>>>(xb, mbuf, lbuf, ab);
  gemm_ao<<<256, 512, 0, stream>>>(ab, wob, out);
}